// Round 14
// baseline (940.344 us; speedup 1.0000x reference)
//
#include <hip/hip_runtime.h>
#include <math.h>

#define N_NODES  100000
#define N_HEDGES 100000
#define N_INC    3200000
#define N_LINKS  262144

typedef unsigned short u16;

constexpr int C1 = 128;     // smooth channel width
constexpr int NBKT = 782;   // ceil(N_NODES / 128)
constexpr int RSV_STRIDE = 16;
constexpr int BCAP = 8192;
constexpr int P1_NB = 400;
constexpr int P1_CHUNK = 8000;

typedef __attribute__((ext_vector_type(8))) short short8;   // 8 bf16 (4 VGPRs)
typedef __attribute__((ext_vector_type(4))) float f32x4;    // MFMA C/D frag

// bf16 <-> fp32 (exact up / RNE down)
__device__ __forceinline__ float b2f1(u16 u) { return __uint_as_float(((unsigned)u) << 16); }
__device__ __forceinline__ float4 b4f(ushort4 u) {
    float4 f;
    f.x = b2f1(u.x); f.y = b2f1(u.y); f.z = b2f1(u.z); f.w = b2f1(u.w);
    return f;
}
__device__ __forceinline__ u16 f2b(float f) {
    unsigned u = __float_as_uint(f);
    u += 0x7FFFu + ((u >> 16) & 1u);   // round-to-nearest-even
    return (u16)(u >> 16);
}

// ---------------- structure: atomic-light bucketed counting sort ----------------

__global__ void k_init2(int* hoff, int* hend, int* rsv) {
    int i = blockIdx.x * blockDim.x + threadIdx.x;
    if (i < N_HEDGES) { hoff[i] = 0; hend[i] = 0; }
    if (i < NBKT * RSV_STRIDE) rsv[i] = 0;
}

__global__ void k_boundary(const int* __restrict__ inc_e, int* __restrict__ hoff,
                           int* __restrict__ hend) {
    int i = blockIdx.x * blockDim.x + threadIdx.x;
    if (i >= N_INC) return;
    int e = inc_e[i];
    if (i == 0 || inc_e[i - 1] != e) hoff[e] = i;
    if (i == N_INC - 1 || inc_e[i + 1] != e) hend[e] = i + 1;
}

__global__ void k_transform_e(const int* __restrict__ hoff, const int* __restrict__ hend,
                              int* __restrict__ de_cnt, float* __restrict__ de_inv) {
    int e = blockIdx.x * blockDim.x + threadIdx.x;
    if (e >= N_HEDGES) return;
    int d = hend[e] - hoff[e];
    de_cnt[e] = d;
    de_inv[e] = (d > 0) ? 1.0f / (float)d : 0.0f;
}

__global__ __launch_bounds__(256) void k_phase1(const int* __restrict__ inc_v,
                                                const int* __restrict__ inc_e,
                                                int* __restrict__ rsv,
                                                uint2* __restrict__ pairs) {
    __shared__ int hist[NBKT];
    __shared__ int base[NBKT];
    const int t = threadIdx.x;
    const int start = blockIdx.x * P1_CHUNK;
    for (int b = t; b < NBKT; b += 256) hist[b] = 0;
    __syncthreads();
    for (int i = start + t; i < start + P1_CHUNK; i += 256)
        atomicAdd(&hist[inc_v[i] >> 7], 1);
    __syncthreads();
    for (int b = t; b < NBKT; b += 256) {
        int c = hist[b];
        base[b] = (c > 0) ? atomicAdd(&rsv[b * RSV_STRIDE], c) : 0;
        hist[b] = 0;
    }
    __syncthreads();
    for (int i = start + t; i < start + P1_CHUNK; i += 256) {
        int v = inc_v[i];
        int e = inc_e[i];
        int b = v >> 7;
        int r = base[b] + atomicAdd(&hist[b], 1);
        if (r < BCAP)
            pairs[(size_t)b * BCAP + r] = make_uint2((unsigned)v, (unsigned)e);
    }
}

__global__ void k_scan_buckets(const int* __restrict__ rsv, int* __restrict__ bucket_base) {
    __shared__ int s[1024];
    int t = threadIdx.x;
    int own = (t < NBKT) ? rsv[t * RSV_STRIDE] : 0;
    s[t] = own;
    __syncthreads();
    for (int off = 1; off < 1024; off <<= 1) {
        int v = (t >= off) ? s[t - off] : 0;
        __syncthreads();
        s[t] += v;
        __syncthreads();
    }
    if (t < NBKT) bucket_base[t] = s[t] - own;
}

__global__ __launch_bounds__(256) void k_phase2(const int* __restrict__ rsv,
                                                const int* __restrict__ bucket_base,
                                                const uint2* __restrict__ pairs,
                                                int* __restrict__ csr_e,
                                                int* __restrict__ dv_cnt,
                                                float* __restrict__ dv_isqrt,
                                                int* __restrict__ noff) {
    __shared__ int cnt[128];
    __shared__ int pfx[128];
    __shared__ int curs[128];
    const int t = threadIdx.x;
    const int b = blockIdx.x;
    int sz = rsv[b * RSV_STRIDE];
    if (sz > BCAP) sz = BCAP;
    const int gbase = bucket_base[b];
    const uint2* mp = pairs + (size_t)b * BCAP;
    if (t < 128) cnt[t] = 0;
    __syncthreads();
    for (int i = t; i < sz; i += 256)
        atomicAdd(&cnt[mp[i].x & 127], 1);
    __syncthreads();
    if (t < 128) pfx[t] = cnt[t];
    __syncthreads();
    for (int off = 1; off < 128; off <<= 1) {
        int v = (t < 128 && t >= off) ? pfx[t - off] : 0;
        __syncthreads();
        if (t < 128) pfx[t] += v;
        __syncthreads();
    }
    if (t < 128) {
        int excl = pfx[t] - cnt[t];
        curs[t] = excl;
        int v = (b << 7) + t;
        if (v < N_NODES) {
            int c = cnt[t];
            dv_cnt[v] = c;
            dv_isqrt[v] = (c > 0) ? 1.0f / sqrtf((float)c) : 0.0f;
            noff[v] = gbase + excl;
        }
    }
    __syncthreads();
    for (int i = t; i < sz; i += 256) {
        uint2 p = mp[i];
        int r = atomicAdd(&curs[p.x & 127], 1);
        csr_e[gbase + r] = (int)p.y;
    }
}

// ---------------- precision prep ----------------

__global__ void k_x2b(const float* __restrict__ X, u16* __restrict__ Xb) {
    int i = blockIdx.x * blockDim.x + threadIdx.x;
    if (i >= N_NODES * C1 / 4) return;
    float4 x = reinterpret_cast<const float4*>(X)[i];
    reinterpret_cast<ushort4*>(Xb)[i] = make_ushort4(f2b(x.x), f2b(x.y), f2b(x.z), f2b(x.w));
}

// W [K][N] fp32 -> transposed hi/lo bf16 planes T [N][K]
__global__ void k_wsplit(const float* __restrict__ W, u16* __restrict__ Thi,
                         u16* __restrict__ Tlo, int K, int N) {
    int i = blockIdx.x * blockDim.x + threadIdx.x;
    if (i >= K * N) return;
    int n = i / K, k = i - n * K;
    float w = W[(size_t)k * N + n];
    u16 h = f2b(w);
    Thi[(size_t)n * K + k] = h;
    Tlo[(size_t)n * K + k] = f2b(w - b2f1(h));
}

// ---------------- feature segment sums (bf16 tables, fp32 accumulate) ----------------

template <bool WS>
__global__ void k_gather_edges_b(const int* __restrict__ hoff, const int* __restrict__ de_cnt,
                                 const int* __restrict__ inc_v, const u16* __restrict__ in,
                                 const float* __restrict__ dv_isqrt, const float* __restrict__ de_inv,
                                 u16* __restrict__ out, float* __restrict__ se) {
    int gw = (blockIdx.x * blockDim.x + threadIdx.x) >> 6;
    int lane = threadIdx.x & 63;
    if (gw >= N_HEDGES) return;
    int half = lane >> 5;
    int l = lane & 31;
    int st = hoff[gw], n = de_cnt[gw];
    float4 acc = {0.f, 0.f, 0.f, 0.f};
    float ws = 0.f;
    int j = half;
    for (; j + 14 < n; j += 16) {
        int v[8]; float w[8]; ushort4 r[8];
#pragma unroll
        for (int q = 0; q < 8; ++q) v[q] = inc_v[st + j + 2 * q];
#pragma unroll
        for (int q = 0; q < 8; ++q) w[q] = dv_isqrt[v[q]];
#pragma unroll
        for (int q = 0; q < 8; ++q)
            r[q] = *reinterpret_cast<const ushort4*>(in + (size_t)v[q] * C1 + l * 4);
#pragma unroll
        for (int q = 0; q < 8; ++q) {
            if (WS) ws += w[q];
            float4 x = b4f(r[q]);
            acc.x = fmaf(w[q], x.x, acc.x); acc.y = fmaf(w[q], x.y, acc.y);
            acc.z = fmaf(w[q], x.z, acc.z); acc.w = fmaf(w[q], x.w, acc.w);
        }
    }
    for (; j < n; j += 2) {
        int v = inc_v[st + j];
        float w = dv_isqrt[v];
        float4 x = b4f(*reinterpret_cast<const ushort4*>(in + (size_t)v * C1 + l * 4));
        if (WS) ws += w;
        acc.x = fmaf(w, x.x, acc.x); acc.y = fmaf(w, x.y, acc.y);
        acc.z = fmaf(w, x.z, acc.z); acc.w = fmaf(w, x.w, acc.w);
    }
    acc.x += __shfl_xor(acc.x, 32);
    acc.y += __shfl_xor(acc.y, 32);
    acc.z += __shfl_xor(acc.z, 32);
    acc.w += __shfl_xor(acc.w, 32);
    if (WS) ws += __shfl_xor(ws, 32);
    if (half == 0) {
        float sc = de_inv[gw];
        *reinterpret_cast<ushort4*>(out + (size_t)gw * C1 + l * 4) =
            make_ushort4(f2b(acc.x * sc), f2b(acc.y * sc), f2b(acc.z * sc), f2b(acc.w * sc));
        if (WS && l == 0) se[gw] = ws * sc;
    }
}

// reads bf16 rows; writes hi/lo bf16 planes (GEMM1 A input); fuses svec
__global__ void k_gather_nodes_b(const int* __restrict__ noff, const int* __restrict__ dv_cnt,
                                 const int* __restrict__ csr_e, const u16* __restrict__ in,
                                 const float* __restrict__ dv_isqrt, u16* __restrict__ out_hi,
                                 u16* __restrict__ out_lo, const float* __restrict__ se,
                                 float* __restrict__ svec) {
    int gw = (blockIdx.x * blockDim.x + threadIdx.x) >> 6;
    int lane = threadIdx.x & 63;
    if (gw >= N_NODES) return;
    int half = lane >> 5;
    int l = lane & 31;
    int st = noff[gw], n = dv_cnt[gw];
    float4 acc = {0.f, 0.f, 0.f, 0.f};
    float sv = 0.f;
    int j = half;
    for (; j + 14 < n; j += 16) {
        int e[8]; ushort4 r[8];
#pragma unroll
        for (int q = 0; q < 8; ++q) e[q] = csr_e[st + j + 2 * q];
#pragma unroll
        for (int q = 0; q < 8; ++q)
            r[q] = *reinterpret_cast<const ushort4*>(in + (size_t)e[q] * C1 + l * 4);
#pragma unroll
        for (int q = 0; q < 8; ++q) {
            sv += se[e[q]];
            float4 y = b4f(r[q]);
            acc.x += y.x; acc.y += y.y; acc.z += y.z; acc.w += y.w;
        }
    }
    for (; j < n; j += 2) {
        int e = csr_e[st + j];
        float4 y = b4f(*reinterpret_cast<const ushort4*>(in + (size_t)e * C1 + l * 4));
        sv += se[e];
        acc.x += y.x; acc.y += y.y; acc.z += y.z; acc.w += y.w;
    }
    acc.x += __shfl_xor(acc.x, 32);
    acc.y += __shfl_xor(acc.y, 32);
    acc.z += __shfl_xor(acc.z, 32);
    acc.w += __shfl_xor(acc.w, 32);
    sv += __shfl_xor(sv, 32);
    if (half == 0) {
        float sc = dv_isqrt[gw];
        float4 o = {acc.x * sc, acc.y * sc, acc.z * sc, acc.w * sc};
        ushort4 hi = make_ushort4(f2b(o.x), f2b(o.y), f2b(o.z), f2b(o.w));
        ushort4 lo = make_ushort4(f2b(o.x - b2f1(hi.x)), f2b(o.y - b2f1(hi.y)),
                                  f2b(o.z - b2f1(hi.z)), f2b(o.w - b2f1(hi.w)));
        *reinterpret_cast<ushort4*>(out_hi + (size_t)gw * C1 + l * 4) = hi;
        *reinterpret_cast<ushort4*>(out_lo + (size_t)gw * C1 + l * 4) = lo;
        if (l == 0) svec[gw] = sv * sc;
    }
}

// final gather + fc head
__global__ void k_gather_nodes_fc_b(const int* __restrict__ noff, const int* __restrict__ dv_cnt,
                                    const int* __restrict__ csr_e, const u16* __restrict__ in,
                                    const float* __restrict__ dv_isqrt, const float* __restrict__ fcW,
                                    float* __restrict__ t) {
    int gw = (blockIdx.x * blockDim.x + threadIdx.x) >> 6;
    int lane = threadIdx.x & 63;
    if (gw >= N_NODES) return;
    int half = lane >> 5;
    int l = lane & 31;
    int st = noff[gw], n = dv_cnt[gw];
    float4 acc = {0.f, 0.f, 0.f, 0.f};
    int j = half;
    for (; j + 14 < n; j += 16) {
        int e[8]; ushort4 r[8];
#pragma unroll
        for (int q = 0; q < 8; ++q) e[q] = csr_e[st + j + 2 * q];
#pragma unroll
        for (int q = 0; q < 8; ++q)
            r[q] = *reinterpret_cast<const ushort4*>(in + (size_t)e[q] * C1 + l * 4);
#pragma unroll
        for (int q = 0; q < 8; ++q) {
            float4 y = b4f(r[q]);
            acc.x += y.x; acc.y += y.y; acc.z += y.z; acc.w += y.w;
        }
    }
    for (; j < n; j += 2) {
        int e = csr_e[st + j];
        float4 y = b4f(*reinterpret_cast<const ushort4*>(in + (size_t)e * C1 + l * 4));
        acc.x += y.x; acc.y += y.y; acc.z += y.z; acc.w += y.w;
    }
    acc.x += __shfl_xor(acc.x, 32);
    acc.y += __shfl_xor(acc.y, 32);
    acc.z += __shfl_xor(acc.z, 32);
    acc.w += __shfl_xor(acc.w, 32);
    float sc = dv_isqrt[gw];
    float4 w = *reinterpret_cast<const float4*>(fcW + l * 4);
    float p = fmaxf(acc.x * sc, 0.f) * w.x + fmaxf(acc.y * sc, 0.f) * w.y +
              fmaxf(acc.z * sc, 0.f) * w.z + fmaxf(acc.w * sc, 0.f) * w.w;
#pragma unroll
    for (int off = 16; off > 0; off >>= 1) p += __shfl_xor(p, off);
    if (lane == 0) t[gw] = p;
}

// ---------------- MFMA GEMM: bf16x2-split, fp32-grade accuracy ----------------
// D = (Ahi+Alo)(Bhi+Blo) ~= Ahi*Bhi + Ahi*Blo + Alo*Bhi  (fp32 accumulate).
// Block = 16 rows x N; 4 waves, each wave NTW 16x16 tiles over N. No LDS.
// Fragment layouts (guide §3, HW-verified m89/m91):
//   A: row = lane&15, k = (lane>>4)*8 + i   (8 contiguous bf16 per lane)
//   B: col = lane&15, k = (lane>>4)*8 + i   (from transposed weight planes)
//   C/D: col = lane&15, row = (lane>>4)*4 + reg
// EPI==1: relu(acc + svec[row]*bias[col]) -> hi/lo planes (H)
// EPI==3: acc + bias[col] -> single bf16 plane (T2b)
template <int K, int NTW, int EPI>
__global__ __launch_bounds__(256) void k_gemm_mfma(
        const u16* __restrict__ Ahi, const u16* __restrict__ Alo,
        const u16* __restrict__ BThi, const u16* __restrict__ BTlo,
        const float* __restrict__ bias, const float* __restrict__ svec,
        u16* __restrict__ outHi, u16* __restrict__ outLo, int N) {
    const int tid = threadIdx.x;
    const int wave = tid >> 6, lane = tid & 63;
    const int bm = blockIdx.x * 16;           // M = 100000 = 6250 * 16, exact
    const int rr = lane & 15;
    const int kg = lane >> 4;
    const int bn = wave * (NTW * 16);

    f32x4 acc[NTW];
#pragma unroll
    for (int t = 0; t < NTW; ++t) acc[t] = {0.f, 0.f, 0.f, 0.f};

    const u16* aph = Ahi + (size_t)(bm + rr) * K + kg * 8;
    const u16* apl = Alo + (size_t)(bm + rr) * K + kg * 8;

    for (int ks = 0; ks < K; ks += 32) {
        short8 ah = *reinterpret_cast<const short8*>(aph + ks);
        short8 al = *reinterpret_cast<const short8*>(apl + ks);
#pragma unroll
        for (int t = 0; t < NTW; ++t) {
            size_t boff = (size_t)(bn + t * 16 + rr) * K + ks + kg * 8;
            short8 bh = *reinterpret_cast<const short8*>(BThi + boff);
            short8 bl = *reinterpret_cast<const short8*>(BTlo + boff);
            acc[t] = __builtin_amdgcn_mfma_f32_16x16x32_bf16(ah, bh, acc[t], 0, 0, 0);
            acc[t] = __builtin_amdgcn_mfma_f32_16x16x32_bf16(ah, bl, acc[t], 0, 0, 0);
            acc[t] = __builtin_amdgcn_mfma_f32_16x16x32_bf16(al, bh, acc[t], 0, 0, 0);
        }
    }

    float sv[4];
    if (EPI == 1) {
#pragma unroll
        for (int r = 0; r < 4; ++r) sv[r] = svec[bm + kg * 4 + r];
    }
#pragma unroll
    for (int t = 0; t < NTW; ++t) {
        int col = bn + t * 16 + rr;
        float bc = bias[col];
#pragma unroll
        for (int r = 0; r < 4; ++r) {
            int row = bm + kg * 4 + r;
            float v = acc[t][r];
            if (EPI == 1) {
                v = fmaxf(fmaf(sv[r], bc, v), 0.f);
                u16 h = f2b(v);
                outHi[(size_t)row * N + col] = h;
                outLo[(size_t)row * N + col] = f2b(v - b2f1(h));
            } else {
                outHi[(size_t)row * N + col] = f2b(v + bc);
            }
        }
    }
}

// ---------------- link head ----------------

__global__ void k_link(const int* __restrict__ link, const float* __restrict__ t,
                       const float* __restrict__ fcb, float* __restrict__ out) {
    int l = blockIdx.x * blockDim.x + threadIdx.x;
    if (l >= N_LINKS) return;
    int a = link[2 * l], b = link[2 * l + 1];
    float x = 0.5f * (t[a] + t[b]) + fcb[0];
    out[l] = 1.f / (1.f + expf(-x));
}

// ---------------- host ----------------

extern "C" void kernel_launch(void* const* d_in, const int* in_sizes, int n_in,
                              void* d_out, int out_size, void* d_ws, size_t ws_size,
                              hipStream_t stream) {
    const float* X    = (const float*)d_in[0];
    const float* W1   = (const float*)d_in[1];
    const float* b1   = (const float*)d_in[2];
    const float* W2   = (const float*)d_in[3];
    const float* b2   = (const float*)d_in[4];
    const float* fcW  = (const float*)d_in[5];
    const float* fcb  = (const float*)d_in[6];
    const int* inc_v  = (const int*)d_in[7];
    const int* inc_e  = (const int*)d_in[8];
    const int* link   = (const int*)d_in[9];
    float* out = (float*)d_out;

    size_t off = 0;
    auto carve = [&](size_t nbytes) -> void* {
        void* p = (char*)d_ws + off;
        off += (nbytes + 255) & ~(size_t)255;
        return p;
    };
    int* hoff    = (int*)carve((size_t)N_HEDGES * 4);
    int* hend    = (int*)carve((size_t)N_HEDGES * 4);
    int* de_cnt  = (int*)carve((size_t)N_HEDGES * 4);
    int* dv_cnt  = (int*)carve((size_t)N_NODES * 4);
    int* noff    = (int*)carve((size_t)N_NODES * 4);
    int* rsv     = (int*)carve((size_t)NBKT * RSV_STRIDE * 4);
    int* bucket_base = (int*)carve((size_t)NBKT * 4);
    float* dv_isqrt = (float*)carve((size_t)N_NODES * 4);
    float* de_inv   = (float*)carve((size_t)N_HEDGES * 4);
    float* se    = (float*)carve((size_t)N_HEDGES * 4);
    float* svec  = (float*)carve((size_t)N_NODES * 4);
    float* tvec  = (float*)carve((size_t)N_NODES * 4);
    int* csr_e   = (int*)carve((size_t)N_INC * 4);
    u16* w1th    = (u16*)carve((size_t)256 * 128 * 2);   // W1^T hi  [256][128]
    u16* w1tl    = (u16*)carve((size_t)256 * 128 * 2);   // W1^T lo
    u16* w2th    = (u16*)carve((size_t)128 * 256 * 2);   // W2^T hi  [128][256]
    u16* w2tl    = (u16*)carve((size_t)128 * 256 * 2);   // W2^T lo
    // R0 (102.4 MB) time-shares: pairs(51.2) -> Yeb1(25.6) -> H_hi(51.2)+H_lo(51.2)
    //   -> Yeb2(25.6).  Xs region (51.2 MB): Xb(25.6) -> Xs_hi(25.6)+Xs_lo(25.6)
    //   -> T2b(25.6).  All lifetimes disjoint in stream order (audited).
    float* R0    = (float*)carve((size_t)N_NODES * 256 * 4);   // 102.4 MB
    float* XsR   = (float*)carve((size_t)N_NODES * C1 * 4);    // 51.2 MB
    uint2* pairs = (uint2*)R0;
    u16*   Yeb   = (u16*)R0;
    u16*   H_hi  = (u16*)R0;                                   // [1e5][256] bf16
    u16*   H_lo  = (u16*)R0 + (size_t)N_NODES * 256;
    u16*   Xb    = (u16*)XsR;
    u16*   Xs_hi = (u16*)XsR;                                  // [1e5][128] bf16
    u16*   Xs_lo = (u16*)XsR + (size_t)N_NODES * C1;
    u16*   T2b   = (u16*)XsR;

    if (off > ws_size) return;   // clean, attributable failure instead of OOB

    // structure
    k_init2<<<(N_HEDGES + 255) / 256, 256, 0, stream>>>(hoff, hend, rsv);
    k_boundary<<<N_INC / 256, 256, 0, stream>>>(inc_e, hoff, hend);
    k_transform_e<<<(N_HEDGES + 255) / 256, 256, 0, stream>>>(hoff, hend, de_cnt, de_inv);
    k_phase1<<<P1_NB, 256, 0, stream>>>(inc_v, inc_e, rsv, pairs);
    k_scan_buckets<<<1, 1024, 0, stream>>>(rsv, bucket_base);
    k_phase2<<<NBKT, 256, 0, stream>>>(rsv, bucket_base, pairs, csr_e, dv_cnt, dv_isqrt, noff);

    // precision prep
    k_x2b<<<(N_NODES * C1 / 4 + 255) / 256, 256, 0, stream>>>(X, Xb);
    k_wsplit<<<(128 * 256 + 255) / 256, 256, 0, stream>>>(W1, w1th, w1tl, 128, 256);
    k_wsplit<<<(256 * 128 + 255) / 256, 256, 0, stream>>>(W2, w2th, w2tl, 256, 128);

    // layer 1: h = relu(smooth(X) @ W1 + s*b1); s = smooth(ones) fused
    k_gather_edges_b<true><<<25000, 256, 0, stream>>>(hoff, de_cnt, inc_v, Xb, dv_isqrt, de_inv, Yeb, se);
    k_gather_nodes_b<<<25000, 256, 0, stream>>>(noff, dv_cnt, csr_e, Yeb, dv_isqrt, Xs_hi, Xs_lo, se, svec);
    k_gemm_mfma<128, 4, 1><<<N_NODES / 16, 256, 0, stream>>>(Xs_hi, Xs_lo, w1th, w1tl, b1, svec, H_hi, H_lo, 256);

    // layer 2: z = relu(smooth(H @ W2 + b2)); fc fused into final gather
    k_gemm_mfma<256, 2, 3><<<N_NODES / 16, 256, 0, stream>>>(H_hi, H_lo, w2th, w2tl, b2, nullptr, T2b, nullptr, 128);
    k_gather_edges_b<false><<<25000, 256, 0, stream>>>(hoff, de_cnt, inc_v, T2b, dv_isqrt, de_inv, Yeb, nullptr);
    k_gather_nodes_fc_b<<<25000, 256, 0, stream>>>(noff, dv_cnt, csr_e, Yeb, dv_isqrt, fcW, tvec);

    // out = sigmoid(0.5*(t[a]+t[b]) + fcb)
    k_link<<<N_LINKS / 256, 256, 0, stream>>>(link, tvec, fcb, out);
}